// Round 12
// baseline (73.580 us; speedup 1.0000x reference)
//
#include <hip/hip_runtime.h>

// Window_Crop: sliding-window avgpool over 5 aspect ratios + argmax (grps 0-3).
//
// Ratios (exact Python float semantics: 1024 // 25.6 == 39.0):
//   g0 (32,32) off 0      OH81 OW81   g1 (25,39) off 6561  OH88 OW74
//   g2 (39,25) off 13073  OH74 OW88   g3 (38,26) off 19585 OH75 OW87
//   g4 (26,38) off 26110  OH87 OW75 (excluded from argmax)  total 32635
//
// R1-R11 model: all barrier-phased structures leave the HBM write stream
// idle during scan/load phases (co-resident blocks run in lockstep) ->
// ~4.7 TB/s effective vs 7 achievable. This version: WAVE SPECIALIZATION.
// grid=256 (1 block/CU), 512 thr. Waves 0-6 = window crew (compute + store
// scores for image n, never stops storing). Wave 7 = scan crew (single wave
// -> rowscan->colscan ordered for free): integral-scans image n+1, stages
// raw load of image n+2. Three 113x116 LDS buffers (157 KB dynamic).
// One barrier per image. PITCH=116, zero-col at col 3: scans use aligned
// float4/float2 LDS ops.

#define B_TOTAL 1024
#define GRID    256
#define IMGS    4
#define HW      112
#define NPIX    (HW * HW)
#define NV4     (NPIX / 4)
#define PITCH   116
#define ISZ     (113 * PITCH)        // 13108 floats = 52,432 B per buffer
#define TOTAL_W 32635
#define BLOCK   512
#define WCREW   448                  // window crew (7 waves)

// image col c (0..111) lives at dword col c+4; zero border col = 3, row = 0.

template<int KH, int KW, int OFF, bool TRACK>
__device__ __forceinline__ void windows_group(const float* __restrict__ S,
                                              float* __restrict__ gout,
                                              int t, float& bv, int& bi) {
    constexpr int OH = HW - KH + 1;
    constexpr int OW = HW - KW + 1;
    constexpr int N  = OH * OW;
    constexpr int D  = KH * PITCH;
    constexpr float inv = 1.0f / (float)(KH * KW);
    for (int w = t; w < N; w += WCREW) {
        const int i = w / OW;             // const divisor -> magic mul
        const int j = w - i * OW;
        const int A = i * PITCH + j + 3;  // col border at 3
        // (A,A+KW) and (A+D,A+D+KW): const offsets -> ds_read2_b32 pairs
        const float s = S[A + D + KW] - S[A + KW] - S[A + D] + S[A];
        const float sc = s * inv;
        gout[OFF + w] = sc;               // stride-1 lanes: packed 256B/wave
        if (TRACK && sc > bv) { bv = sc; bi = OFF + w; }
    }
}

__device__ __forceinline__ void load_img_g(const float* __restrict__ x, int b,
                                           float* __restrict__ S, int t0, int nt) {
    const float4* img4 = (const float4*)(x + (size_t)b * NPIX);
    for (int i = t0; i < NV4; i += nt) {
        const int r  = i / 28;            // 28 float4 per image row
        const int c4 = (i - r * 28) * 4;
        const float4 v = img4[i];
        *(float4*)&S[(r + 1) * PITCH + 4 + c4] = v;   // 16B-aligned ds_write
    }
}

__device__ __forceinline__ void rowscan_g(float* __restrict__ S, int t0, int nt) {
    for (int r = t0; r < HW; r += nt) {   // full-serial prefix per row
        float run = 0.0f;
        float* row = &S[(r + 1) * PITCH + 4];
        #pragma unroll
        for (int k = 0; k < 28; ++k) {
            float4 p = *(float4*)&row[4 * k];        // aligned b128
            p.x += run; p.y += p.x; p.z += p.y; p.w += p.z; run = p.w;
            *(float4*)&row[4 * k] = p;
        }
    }
}

__device__ __forceinline__ void colscan_g(float* __restrict__ S, int t0, int nt) {
    for (int c2 = t0; c2 < HW / 2; c2 += nt) {   // col pair, serial down rows
        float2 run = make_float2(0.0f, 0.0f);
        float* col = &S[4 + 2 * c2];
        #pragma unroll 4
        for (int r = 1; r <= HW; ++r) {
            float2 v = *(float2*)&col[r * PITCH];    // 8B-aligned b64
            run.x += v.x; run.y += v.y;
            *(float2*)&col[r * PITCH] = run;
        }
    }
}

__global__ __launch_bounds__(BLOCK)
void window_crop_kernel(const float* __restrict__ x, float* __restrict__ out) {
    extern __shared__ float smem[];          // 3 * ISZ floats (157,296 B)
    __shared__ float wv[2][8];
    __shared__ int   wi[2][8];

    const int tid  = threadIdx.x;
    const int lane = tid & 63;
    const int b0   = blockIdx.x * IMGS;

    // zero borders of all 3 buffers: row 0 (cols 3..115) and col 3 (rows 0..112)
    for (int i = tid; i < PITCH; i += BLOCK) {
        for (int q = 0; q < 3; ++q) {
            smem[q * ISZ + i] = 0.0f;
            if (i < 113) smem[q * ISZ + i * PITCH + 3] = 0.0f;
        }
    }
    __syncthreads();

    // ---- prologue ----
    load_img_g(x, b0 + 0, smem, tid, BLOCK);
    __syncthreads();
    if (tid < WCREW) rowscan_g(smem, tid, WCREW);
    else             load_img_g(x, b0 + 1, smem + ISZ, tid - WCREW, 64);
    __syncthreads();
    if (tid < WCREW) colscan_g(smem, tid, WCREW);
    __syncthreads();

    // ---- steady state: windows(n) || {scan(n+1), load(n+2)} ----
    for (int n = 0; n < IMGS; ++n) {
        const int par = n & 1;
        if (tid < WCREW) {
            // finish previous image's argmax (reads wv[par^1], no race)
            if (tid == 0 && n > 0) {
                float bv = wv[par ^ 1][0]; int bi = wi[par ^ 1][0];
                #pragma unroll
                for (int k = 1; k < 7; ++k) {
                    if (wv[par ^ 1][k] > bv ||
                        (wv[par ^ 1][k] == bv && wi[par ^ 1][k] < bi)) {
                        bv = wv[par ^ 1][k]; bi = wi[par ^ 1][k];
                    }
                }
                out[b0 + n - 1]           = (float)bi;
                out[B_TOTAL + b0 + n - 1] = bv;
            }
            const float* Sn = smem + (n % 3) * ISZ;
            float* gout = out + 2 * B_TOTAL + (size_t)(b0 + n) * TOTAL_W;
            float bestv = -3.402823466e+38f;
            int   besti = 0;
            windows_group<32, 32,     0, true >(Sn, gout, tid, bestv, besti);
            windows_group<25, 39,  6561, true >(Sn, gout, tid, bestv, besti);
            windows_group<39, 25, 13073, true >(Sn, gout, tid, bestv, besti);
            windows_group<38, 26, 19585, true >(Sn, gout, tid, bestv, besti);
            windows_group<26, 38, 26110, false>(Sn, gout, tid, bestv, besti);
            #pragma unroll
            for (int d = 32; d > 0; d >>= 1) {
                const float ov = __shfl_down(bestv, d, 64);
                const int   oi = __shfl_down(besti, d, 64);
                if (ov > bestv || (ov == bestv && oi < besti)) { bestv = ov; besti = oi; }
            }
            if (lane == 0) { wv[par][tid >> 6] = bestv; wi[par][tid >> 6] = besti; }
        } else {
            const int st = tid - WCREW;          // scan crew: single wave
            if (n + 1 < IMGS) {
                float* Sx = smem + ((n + 1) % 3) * ISZ;
                rowscan_g(Sx, st, 64);           // same wave: ordered for free
                colscan_g(Sx, st, 64);
            }
            if (n + 2 < IMGS)
                load_img_g(x, b0 + n + 2, smem + ((n + 2) % 3) * ISZ, st, 64);
        }
        __syncthreads();
    }

    // final image's argmax
    if (tid == 0) {
        const int par = (IMGS - 1) & 1;
        float bv = wv[par][0]; int bi = wi[par][0];
        #pragma unroll
        for (int k = 1; k < 7; ++k) {
            if (wv[par][k] > bv || (wv[par][k] == bv && wi[par][k] < bi)) {
                bv = wv[par][k]; bi = wi[par][k];
            }
        }
        out[b0 + IMGS - 1]           = (float)bi;
        out[B_TOTAL + b0 + IMGS - 1] = bv;
    }
}

extern "C" void kernel_launch(void* const* d_in, const int* in_sizes, int n_in,
                              void* d_out, int out_size, void* d_ws, size_t ws_size,
                              hipStream_t stream) {
    const float* x = (const float*)d_in[0];
    float* out     = (float*)d_out;
    window_crop_kernel<<<GRID, BLOCK, 3 * ISZ * sizeof(float), stream>>>(x, out);
}

// Round 13
// 73.474 us; speedup vs baseline: 1.0014x; 1.0014x over previous
//
#include <hip/hip_runtime.h>

// Window_Crop: sliding-window avgpool over 5 aspect ratios + argmax (grps 0-3).
//
// Ratios (exact Python float semantics: 1024 // 25.6 == 39.0):
//   g0 (32,32) off 0      OH81 OW81   g1 (25,39) off 6561  OH88 OW74
//   g2 (39,25) off 13073  OH74 OW88   g3 (38,26) off 19585 OH75 OW87
//   g4 (26,38) off 26110  OH87 OW75 (excluded from argmax)  total 32635
//
// R1-R11 model: all barrier-phased structures leave the HBM write stream
// idle during scan/load phases (co-resident blocks run in lockstep) ->
// ~4.7 TB/s effective vs 7 achievable. This version: WAVE SPECIALIZATION.
// grid=256 (1 block/CU), 512 thr. Waves 0-6 = window crew (compute + store
// scores for image n, never stops storing). Wave 7 = scan crew (single wave
// -> rowscan->colscan ordered for free): integral-scans image n+1, stages
// raw load of image n+2. Three 113x116 LDS buffers (157 KB dynamic).
// One barrier per image. PITCH=116, zero-col at col 3: scans use aligned
// float4/float2 LDS ops.

#define B_TOTAL 1024
#define GRID    256
#define IMGS    4
#define HW      112
#define NPIX    (HW * HW)
#define NV4     (NPIX / 4)
#define PITCH   116
#define ISZ     (113 * PITCH)        // 13108 floats = 52,432 B per buffer
#define TOTAL_W 32635
#define BLOCK   512
#define WCREW   448                  // window crew (7 waves)

// image col c (0..111) lives at dword col c+4; zero border col = 3, row = 0.

template<int KH, int KW, int OFF, bool TRACK>
__device__ __forceinline__ void windows_group(const float* __restrict__ S,
                                              float* __restrict__ gout,
                                              int t, float& bv, int& bi) {
    constexpr int OH = HW - KH + 1;
    constexpr int OW = HW - KW + 1;
    constexpr int N  = OH * OW;
    constexpr int D  = KH * PITCH;
    constexpr float inv = 1.0f / (float)(KH * KW);
    for (int w = t; w < N; w += WCREW) {
        const int i = w / OW;             // const divisor -> magic mul
        const int j = w - i * OW;
        const int A = i * PITCH + j + 3;  // col border at 3
        // (A,A+KW) and (A+D,A+D+KW): const offsets -> ds_read2_b32 pairs
        const float s = S[A + D + KW] - S[A + KW] - S[A + D] + S[A];
        const float sc = s * inv;
        gout[OFF + w] = sc;               // stride-1 lanes: packed 256B/wave
        if (TRACK && sc > bv) { bv = sc; bi = OFF + w; }
    }
}

__device__ __forceinline__ void load_img_g(const float* __restrict__ x, int b,
                                           float* __restrict__ S, int t0, int nt) {
    const float4* img4 = (const float4*)(x + (size_t)b * NPIX);
    for (int i = t0; i < NV4; i += nt) {
        const int r  = i / 28;            // 28 float4 per image row
        const int c4 = (i - r * 28) * 4;
        const float4 v = img4[i];
        *(float4*)&S[(r + 1) * PITCH + 4 + c4] = v;   // 16B-aligned ds_write
    }
}

__device__ __forceinline__ void rowscan_g(float* __restrict__ S, int t0, int nt) {
    for (int r = t0; r < HW; r += nt) {   // full-serial prefix per row
        float run = 0.0f;
        float* row = &S[(r + 1) * PITCH + 4];
        #pragma unroll
        for (int k = 0; k < 28; ++k) {
            float4 p = *(float4*)&row[4 * k];        // aligned b128
            p.x += run; p.y += p.x; p.z += p.y; p.w += p.z; run = p.w;
            *(float4*)&row[4 * k] = p;
        }
    }
}

__device__ __forceinline__ void colscan_g(float* __restrict__ S, int t0, int nt) {
    for (int c2 = t0; c2 < HW / 2; c2 += nt) {   // col pair, serial down rows
        float2 run = make_float2(0.0f, 0.0f);
        float* col = &S[4 + 2 * c2];
        #pragma unroll 4
        for (int r = 1; r <= HW; ++r) {
            float2 v = *(float2*)&col[r * PITCH];    // 8B-aligned b64
            run.x += v.x; run.y += v.y;
            *(float2*)&col[r * PITCH] = run;
        }
    }
}

__global__ __launch_bounds__(BLOCK)
void window_crop_kernel(const float* __restrict__ x, float* __restrict__ out) {
    extern __shared__ float smem[];          // 3 * ISZ floats (157,296 B)
    __shared__ float wv[2][8];
    __shared__ int   wi[2][8];

    const int tid  = threadIdx.x;
    const int lane = tid & 63;
    const int b0   = blockIdx.x * IMGS;

    // zero borders of all 3 buffers: row 0 (cols 3..115) and col 3 (rows 0..112)
    for (int i = tid; i < PITCH; i += BLOCK) {
        for (int q = 0; q < 3; ++q) {
            smem[q * ISZ + i] = 0.0f;
            if (i < 113) smem[q * ISZ + i * PITCH + 3] = 0.0f;
        }
    }
    __syncthreads();

    // ---- prologue ----
    load_img_g(x, b0 + 0, smem, tid, BLOCK);
    __syncthreads();
    if (tid < WCREW) rowscan_g(smem, tid, WCREW);
    else             load_img_g(x, b0 + 1, smem + ISZ, tid - WCREW, 64);
    __syncthreads();
    if (tid < WCREW) colscan_g(smem, tid, WCREW);
    __syncthreads();

    // ---- steady state: windows(n) || {scan(n+1), load(n+2)} ----
    for (int n = 0; n < IMGS; ++n) {
        const int par = n & 1;
        if (tid < WCREW) {
            // finish previous image's argmax (reads wv[par^1], no race)
            if (tid == 0 && n > 0) {
                float bv = wv[par ^ 1][0]; int bi = wi[par ^ 1][0];
                #pragma unroll
                for (int k = 1; k < 7; ++k) {
                    if (wv[par ^ 1][k] > bv ||
                        (wv[par ^ 1][k] == bv && wi[par ^ 1][k] < bi)) {
                        bv = wv[par ^ 1][k]; bi = wi[par ^ 1][k];
                    }
                }
                out[b0 + n - 1]           = (float)bi;
                out[B_TOTAL + b0 + n - 1] = bv;
            }
            const float* Sn = smem + (n % 3) * ISZ;
            float* gout = out + 2 * B_TOTAL + (size_t)(b0 + n) * TOTAL_W;
            float bestv = -3.402823466e+38f;
            int   besti = 0;
            windows_group<32, 32,     0, true >(Sn, gout, tid, bestv, besti);
            windows_group<25, 39,  6561, true >(Sn, gout, tid, bestv, besti);
            windows_group<39, 25, 13073, true >(Sn, gout, tid, bestv, besti);
            windows_group<38, 26, 19585, true >(Sn, gout, tid, bestv, besti);
            windows_group<26, 38, 26110, false>(Sn, gout, tid, bestv, besti);
            #pragma unroll
            for (int d = 32; d > 0; d >>= 1) {
                const float ov = __shfl_down(bestv, d, 64);
                const int   oi = __shfl_down(besti, d, 64);
                if (ov > bestv || (ov == bestv && oi < besti)) { bestv = ov; besti = oi; }
            }
            if (lane == 0) { wv[par][tid >> 6] = bestv; wi[par][tid >> 6] = besti; }
        } else {
            const int st = tid - WCREW;          // scan crew: single wave
            if (n + 1 < IMGS) {
                float* Sx = smem + ((n + 1) % 3) * ISZ;
                rowscan_g(Sx, st, 64);           // same wave: ordered for free
                colscan_g(Sx, st, 64);
            }
            if (n + 2 < IMGS)
                load_img_g(x, b0 + n + 2, smem + ((n + 2) % 3) * ISZ, st, 64);
        }
        __syncthreads();
    }

    // final image's argmax
    if (tid == 0) {
        const int par = (IMGS - 1) & 1;
        float bv = wv[par][0]; int bi = wi[par][0];
        #pragma unroll
        for (int k = 1; k < 7; ++k) {
            if (wv[par][k] > bv || (wv[par][k] == bv && wi[par][k] < bi)) {
                bv = wv[par][k]; bi = wi[par][k];
            }
        }
        out[b0 + IMGS - 1]           = (float)bi;
        out[B_TOTAL + b0 + IMGS - 1] = bv;
    }
}

extern "C" void kernel_launch(void* const* d_in, const int* in_sizes, int n_in,
                              void* d_out, int out_size, void* d_ws, size_t ws_size,
                              hipStream_t stream) {
    const float* x = (const float*)d_in[0];
    float* out     = (float*)d_out;
    window_crop_kernel<<<GRID, BLOCK, 3 * ISZ * sizeof(float), stream>>>(x, out);
}

// Round 14
// 38.960 us; speedup vs baseline: 1.8886x; 1.8859x over previous
//
#include <hip/hip_runtime.h>

// Window_Crop: per-batch sliding-window average pooling over 5 aspect ratios
// (stride 1) + argmax over first 4 ratio groups.
//
// Ratios (exact Python float semantics: 1024 // 25.6 == 39.0):
//   (32,32) N=6561  off 0
//   (25,39) N=6512  off 6561
//   (39,25) N=6512  off 13073
//   (38,26) N=6525  off 19585
//   (26,38) N=6525  off 26110   (excluded from argmax)
//   total 32635
//
// Base = R7 (best, 39.1us): 512 blocks x 2 images, 51KB LDS -> 2 blocks/CU,
// T14 prefetch of image B, stride-1 scalar window stores.
// R14 change: ALL __syncthreads() -> "s_waitcnt lgkmcnt(0); s_barrier".
// Cross-thread deps in this kernel are LDS-only (score stores go to disjoint
// global addresses, never re-read), so the vmcnt(0) drain that __syncthreads
// emits is unnecessary -- it stalled the global store queue at every barrier
// (~10 per 2-image step). Now stores stay in flight across barriers.

#define B_TOTAL 1024
#define GRID    512
#define HW      112
#define NPIX    (HW * HW)
#define NV4     (NPIX / 4)           // 3136 float4 per image
#define PITCH   113
#define TOTAL_W 32635
#define BLOCK   512
#define LDV4    7                    // ceil(3136 / 512)
#define SEG     28                   // 112 / 4 segments per scan line

// LDS-only barrier: waits LDS/shfl ops, NOT the global store queue.
#define BAR() asm volatile("s_waitcnt lgkmcnt(0)\n\ts_barrier" ::: "memory")

template<int KH, int KW, int OFF, bool TRACK>
__device__ __forceinline__ void windows_group(const float* __restrict__ S,
                                              float* __restrict__ out_scores,
                                              int tid, float& bestv, int& besti) {
    constexpr int OH = HW - KH + 1;
    constexpr int OW = HW - KW + 1;
    constexpr int N  = OH * OW;
    constexpr int D  = KH * PITCH;        // bottom-row offset (dwords)
    constexpr float inv = 1.0f / (float)(KH * KW);
    for (int w = tid; w < N; w += BLOCK) {
        const int i  = w / OW;            // const divisor -> magic mul
        const int j  = w - i * OW;
        const int A  = i * PITCH + j;     // top-left corner
        const int Ab = A + D;             // bottom-left corner
        const float s = S[Ab + KW] - S[A + KW] - S[Ab] + S[A];
        const float sc = s * inv;
        out_scores[OFF + w] = sc;         // lanes stride-1: packed 256B/wave
        if (TRACK && sc > bestv) { bestv = sc; besti = OFF + w; }
    }
}

__device__ __forceinline__ void scans(float* __restrict__ S, int tid, int bl) {
    // row-wise prefix sums: 112 rows x 4 segments of 28; partials in regs,
    // shfl fixup. 113-stride across threads: gcd(17,32)=1 -> conflict-free.
    if (tid < HW * 4) {
        const int r = tid >> 2, s = tid & 3;
        float* row = &S[(r + 1) * PITCH];
        const int c0 = 1 + s * SEG;
        float pref[SEG];
        float run = 0.0f;
        #pragma unroll
        for (int k = 0; k < SEG; ++k) { run += row[c0 + k]; pref[k] = run; }
        const float v0 = __shfl(run, bl, 64), v1 = __shfl(run, bl + 1, 64),
                    v2 = __shfl(run, bl + 2, 64);
        float off = 0.0f;
        if (s > 0) off += v0;
        if (s > 1) off += v1;
        if (s > 2) off += v2;
        #pragma unroll
        for (int k = 0; k < SEG; ++k) row[c0 + k] = pref[k] + off;
    }
    BAR();
    // column-wise prefix sums, same scheme (consecutive addrs across threads)
    if (tid < HW * 4) {
        const int c = tid >> 2, s = tid & 3;
        float* col = &S[c + 1];
        const int r0 = 1 + s * SEG;
        float pref[SEG];
        float run = 0.0f;
        #pragma unroll
        for (int k = 0; k < SEG; ++k) { run += col[(r0 + k) * PITCH]; pref[k] = run; }
        const float v0 = __shfl(run, bl, 64), v1 = __shfl(run, bl + 1, 64),
                    v2 = __shfl(run, bl + 2, 64);
        float off = 0.0f;
        if (s > 0) off += v0;
        if (s > 1) off += v1;
        if (s > 2) off += v2;
        #pragma unroll
        for (int k = 0; k < SEG; ++k) col[(r0 + k) * PITCH] = pref[k] + off;
    }
    BAR();
}

__device__ __forceinline__ void write_img(float* __restrict__ S, const float4* v,
                                          int tid) {
    #pragma unroll
    for (int k = 0; k < LDV4; ++k) {
        const int i = tid + k * BLOCK;
        if (i < NV4) {
            const int r = i / (HW / 4);
            const int c = (i - r * (HW / 4)) * 4;
            float* dst = &S[(r + 1) * PITCH + (c + 1)];
            dst[0] = v[k].x; dst[1] = v[k].y; dst[2] = v[k].z; dst[3] = v[k].w;
        }
    }
}

__device__ __forceinline__ void windows_phase(const float* __restrict__ S,
                                              float* __restrict__ out, int b,
                                              int tid, int lane,
                                              float* wv, int* wi) {
    float bestv = -3.402823466e+38f;
    int   besti = 0;
    float* out_scores = out + 2 * B_TOTAL + (size_t)b * TOTAL_W;

    windows_group<32, 32,     0, true >(S, out_scores, tid, bestv, besti);
    windows_group<25, 39,  6561, true >(S, out_scores, tid, bestv, besti);
    windows_group<39, 25, 13073, true >(S, out_scores, tid, bestv, besti);
    windows_group<38, 26, 19585, true >(S, out_scores, tid, bestv, besti);
    windows_group<26, 38, 26110, false>(S, out_scores, tid, bestv, besti);

    #pragma unroll
    for (int d = 32; d > 0; d >>= 1) {
        const float ov = __shfl_down(bestv, d, 64);
        const int   oi = __shfl_down(besti, d, 64);
        if (ov > bestv || (ov == bestv && oi < besti)) { bestv = ov; besti = oi; }
    }
    if (lane == 0) { wv[tid >> 6] = bestv; wi[tid >> 6] = besti; }
    BAR();
    if (tid == 0) {
        float bv = wv[0]; int bi = wi[0];
        #pragma unroll
        for (int k = 1; k < BLOCK / 64; ++k) {
            if (wv[k] > bv || (wv[k] == bv && wi[k] < bi)) { bv = wv[k]; bi = wi[k]; }
        }
        out[b]           = (float)bi;    // idx (exact in fp32: < 2^24)
        out[B_TOTAL + b] = bv;           // prop_scores
    }
}

__global__ __launch_bounds__(BLOCK)
void window_crop_kernel(const float* __restrict__ x, float* __restrict__ out) {
    __shared__ float S[PITCH * PITCH];           // 51,076 B integral image
    __shared__ float wv[BLOCK / 64];
    __shared__ int   wi[BLOCK / 64];

    const int tid  = threadIdx.x;
    const int lane = tid & 63;
    const int bl   = lane & ~3;

    const int bA = blockIdx.x;
    const int bB = blockIdx.x + GRID;

    // zero border row/col once; images only touch [1..112]^2
    for (int i = tid; i < PITCH; i += BLOCK) {
        S[i] = 0.0f;
        S[i * PITCH] = 0.0f;
    }

    // ---- image A: load -> LDS -> scans ----
    float4 va[LDV4];
    const float4* imgA = (const float4*)(x + (size_t)bA * NPIX);
    #pragma unroll
    for (int k = 0; k < LDV4; ++k) {
        const int i = tid + k * BLOCK;
        if (i < NV4) va[k] = imgA[i];
    }
    write_img(S, va, tid);
    BAR();
    scans(S, tid, bl);

    // ---- issue image B's loads (consumed after A's window phase) ----
    float4 vb[LDV4];
    const float4* imgB = (const float4*)(x + (size_t)bB * NPIX);
    #pragma unroll
    for (int k = 0; k < LDV4; ++k) {
        const int i = tid + k * BLOCK;
        if (i < NV4) vb[k] = imgB[i];
    }

    // ---- image A: windows + argmax (write-heavy; B loads in flight) ----
    windows_phase(S, out, bA, tid, lane, wv, wi);
    BAR();                           // all window LDS reads of S done

    // ---- image B: LDS -> scans -> windows ----
    write_img(S, vb, tid);
    BAR();
    scans(S, tid, bl);
    windows_phase(S, out, bB, tid, lane, wv, wi);
}

extern "C" void kernel_launch(void* const* d_in, const int* in_sizes, int n_in,
                              void* d_out, int out_size, void* d_ws, size_t ws_size,
                              hipStream_t stream) {
    const float* x = (const float*)d_in[0];
    float* out     = (float*)d_out;
    window_crop_kernel<<<GRID, BLOCK, 0, stream>>>(x, out);
}